// Round 3
// baseline (796.463 us; speedup 1.0000x reference)
//
#include <hip/hip_runtime.h>
#include <cstdint>
#include <cstddef>

#define F_IN 512
#define F_HID 32
#define N_CLS 16

// ---------------- edge dtype detection (int32 vs int64) ----------------
__global__ void k_detect(const int* e, int* flag) {
    if (threadIdx.x == 0 && blockIdx.x == 0) {
        int zeros = 0;
        for (int i = 0; i < 1024; ++i) if (e[2 * i + 1] == 0) zeros++;
        *flag = (zeros >= 1016) ? 1 : 0;
    }
}

__device__ __forceinline__ int edge_get(const void* e, int is64, long long idx) {
    return is64 ? (int)((const long long*)e)[idx] : ((const int*)e)[idx];
}

// ---------------- degree histogram ----------------
__global__ void k_hist(const void* edges, const int* flag, int* counts, int E) {
    int is64 = *flag;
    long long i = (long long)blockIdx.x * blockDim.x + threadIdx.x;
    long long step = (long long)gridDim.x * blockDim.x;
    for (; i < E; i += step) {
        int d = edge_get(edges, is64, (long long)E + i);
        atomicAdd(&counts[d], 1);
    }
}

// ---------------- dinv = rsqrt(deg+1) ----------------
__global__ void k_dinv(const int* counts, float* dinv, int n) {
    int i = blockIdx.x * blockDim.x + threadIdx.x;
    if (i < n) dinv[i] = rsqrtf((float)counts[i] + 1.0f);
}

// ---------------- 3-kernel exclusive scan (chunk = 1024/block) ----------------
__global__ void k_scan1(const int* counts, int* bsums, int n) {
    int base = blockIdx.x * 1024;
    int t = threadIdx.x;
    int s = 0;
#pragma unroll
    for (int j = 0; j < 4; ++j) {
        int i = base + t * 4 + j;
        if (i < n) s += counts[i];
    }
#pragma unroll
    for (int off = 32; off; off >>= 1) s += __shfl_down(s, off, 64);
    __shared__ int ws[4];
    if ((t & 63) == 0) ws[t >> 6] = s;
    __syncthreads();
    if (t == 0) bsums[blockIdx.x] = ws[0] + ws[1] + ws[2] + ws[3];
}

__global__ void k_scan2(int* bsums, int nb) {  // single block, 128 threads, nb<=128
    __shared__ int tmp[128];
    int t = threadIdx.x;
    int v = (t < nb) ? bsums[t] : 0;
    tmp[t] = v;
    __syncthreads();
    for (int off = 1; off < 128; off <<= 1) {
        int add = (t >= off) ? tmp[t - off] : 0;
        __syncthreads();
        tmp[t] += add;
        __syncthreads();
    }
    if (t < nb) bsums[t] = tmp[t] - v;  // exclusive
}

__global__ void k_scan3(const int* counts, const int* bsums, int* row_ptr, int n, int E) {
    int base = blockIdx.x * 1024;
    int t = threadIdx.x, lane = t & 63, wid = t >> 6;
    int c[4];
    int tsum = 0;
#pragma unroll
    for (int j = 0; j < 4; ++j) {
        int i = base + t * 4 + j;
        c[j] = (i < n) ? counts[i] : 0;
        tsum += c[j];
    }
    int incl = tsum;
#pragma unroll
    for (int off = 1; off < 64; off <<= 1) {
        int u = __shfl_up(incl, off, 64);
        if (lane >= off) incl += u;
    }
    __shared__ int ws[4];
    if (lane == 63) ws[wid] = incl;
    __syncthreads();
    int woff = 0;
#pragma unroll
    for (int wv = 0; wv < 4; ++wv)
        if (wv < wid) woff += ws[wv];
    int excl = incl - tsum + woff + bsums[blockIdx.x];
#pragma unroll
    for (int j = 0; j < 4; ++j) {
        int i = base + t * 4 + j;
        if (i < n) row_ptr[i] = excl;
        excl += c[j];
    }
    if (blockIdx.x == 0 && t == 0) row_ptr[n] = E;
}

// ---------------- CSR fill: dst-range partitioned (8 passes over reg-cached edges) ----
// Each thread caches its <=13 (src,dst) pairs in registers (one coalesced read of the
// edge list), then performs 8 range passes so csr writes cluster into 1.6 MB slices
// that stay L2-resident -> lines absorb all their stores before eviction.
#define FILL_K 13
__global__ __launch_bounds__(256) void k_fill(const void* edges, const int* flag,
                                              const int* __restrict__ row_ptr,
                                              int* cursor, int* __restrict__ csr,
                                              int E, int N) {
    int is64 = *flag;
    long long tid = (long long)blockIdx.x * blockDim.x + threadIdx.x;
    long long stride = (long long)gridDim.x * blockDim.x;
    int ds[FILL_K], ss[FILL_K];
#pragma unroll
    for (int j = 0; j < FILL_K; ++j) {
        long long i = tid + (long long)j * stride;
        if (i < E) {
            ds[j] = edge_get(edges, is64, (long long)E + i);
            ss[j] = edge_get(edges, is64, i);
        } else {
            ds[j] = -1; ss[j] = 0;
        }
    }
    int rsz = (N + 7) / 8;
    for (int r = 0; r < 8; ++r) {
        int lo = r * rsz, hi = lo + rsz;
#pragma unroll
        for (int j = 0; j < FILL_K; ++j) {
            int d = ds[j];
            if (d >= lo && d < hi) {
                int p = row_ptr[d] + atomicAdd(&cursor[d], 1);
                csr[p] = ss[j];
            }
        }
    }
}

// ---------------- GEMM1: hs1 = (x @ W1) * dinv[row]  [N,512]x[512,32] ----------------
// Block = 64 rows x 4 waves; wave w computes K-slice [128w,128w+128) (W index stays
// wave-uniform -> s_load), LDS reduce across waves.
__global__ __launch_bounds__(256) void k_gemm1(const float* __restrict__ x,
                                               const float* __restrict__ W,
                                               const float* __restrict__ dinv,
                                               float* __restrict__ hs1, int N) {
    __shared__ float red[4][64][33];  // +1 pad: conflict-free lane-major access
    int t = threadIdx.x;
    int wv = t >> 6, lane = t & 63;
    int row0 = blockIdx.x * 64;
    int row = row0 + lane;

    float acc[32];
#pragma unroll
    for (int c = 0; c < 32; ++c) acc[c] = 0.f;

    if (row < N) {
        const float4* xr = (const float4*)(x + (size_t)row * F_IN) + wv * 32;
        const float* Wb = W + wv * 128 * 32;
        float4 v = xr[0];
        for (int k4 = 0; k4 < 32; ++k4) {
            float4 nv = (k4 < 31) ? xr[k4 + 1] : v;  // 1-deep prefetch
            const float* wr = Wb + k4 * 128;
#pragma unroll
            for (int c = 0; c < 32; ++c) {
                acc[c] = fmaf(v.x, wr[c], acc[c]);
                acc[c] = fmaf(v.y, wr[32 + c], acc[c]);
                acc[c] = fmaf(v.z, wr[64 + c], acc[c]);
                acc[c] = fmaf(v.w, wr[96 + c], acc[c]);
            }
            v = nv;
        }
    }
#pragma unroll
    for (int c = 0; c < 32; ++c) red[wv][lane][c] = acc[c];
    __syncthreads();
    // 64*32 = 2048 outputs, 8 per thread
#pragma unroll
    for (int j = 0; j < 8; ++j) {
        int o = t * 8 + j;
        int r = o >> 5, c = o & 31;
        int rr = row0 + r;
        if (rr < N) {
            float s = red[0][r][c] + red[1][r][c] + red[2][r][c] + red[3][r][c];
            hs1[(size_t)rr * F_HID + c] = s * dinv[rr];
        }
    }
}

// ---------------- gather layer 1: out1 = relu(dinv*(hs1_self + sum hs1[src]) + b1) ----
__global__ __launch_bounds__(256) void k_gather1(const float* __restrict__ hs1,
                                                 const int* __restrict__ csr,
                                                 const int* __restrict__ row_ptr,
                                                 const float* __restrict__ dinv,
                                                 const float* __restrict__ b1,
                                                 float* __restrict__ out1, int N) {
    int node = blockIdx.x * 4 + (threadIdx.x >> 6);
    if (node >= N) return;
    int lane = threadIdx.x & 63;
    int half = lane >> 5, c = lane & 31;
    int beg = row_ptr[node], end = row_ptr[node + 1];
    float a0 = 0.f, a1 = 0.f;
    int e = beg + half;
    while (e + 2 < end) {
        int s0 = csr[e], s1 = csr[e + 2];
        a0 += hs1[(size_t)s0 * F_HID + c];
        a1 += hs1[(size_t)s1 * F_HID + c];
        e += 4;
    }
    if (e < end) a0 += hs1[(size_t)csr[e] * F_HID + c];
    float acc = a0 + a1;
    acc += __shfl_xor(acc, 32, 64);
    float self = hs1[(size_t)node * F_HID + c];
    float v = dinv[node] * (acc + self) + b1[c];
    v = fmaxf(v, 0.f);
    if (half == 0) out1[(size_t)node * F_HID + c] = v;
}

// ---------------- GEMM2: hs2 = (out1 @ W2) * dinv  [N,32]x[32,16] ----------------
__global__ __launch_bounds__(256) void k_gemm2(const float* __restrict__ in,
                                               const float* __restrict__ W,
                                               const float* __restrict__ dinv,
                                               float* __restrict__ hs2, int N) {
    int row = blockIdx.x * 256 + threadIdx.x;
    if (row >= N) return;
    const float4* xr = (const float4*)(in + (size_t)row * F_HID);
    float acc[16];
#pragma unroll
    for (int c = 0; c < 16; ++c) acc[c] = 0.f;
#pragma unroll
    for (int k4 = 0; k4 < 8; ++k4) {
        float4 xv = xr[k4];
        const float* wr = W + k4 * 64;
#pragma unroll
        for (int c = 0; c < 16; ++c) {
            acc[c] = fmaf(xv.x, wr[c], acc[c]);
            acc[c] = fmaf(xv.y, wr[16 + c], acc[c]);
            acc[c] = fmaf(xv.z, wr[32 + c], acc[c]);
            acc[c] = fmaf(xv.w, wr[48 + c], acc[c]);
        }
    }
    float di = dinv[row];
    float* o = hs2 + (size_t)row * N_CLS;
#pragma unroll
    for (int c = 0; c < 16; c += 4) {
        float4 v = make_float4(acc[c] * di, acc[c + 1] * di, acc[c + 2] * di, acc[c + 3] * di);
        *(float4*)(o + c) = v;
    }
}

// ---------------- gather layer 2 + bias + log_softmax ----------------
__global__ __launch_bounds__(256) void k_gather2(const float* __restrict__ hs2,
                                                 const int* __restrict__ csr,
                                                 const int* __restrict__ row_ptr,
                                                 const float* __restrict__ dinv,
                                                 const float* __restrict__ b2,
                                                 float* __restrict__ out, int N) {
    int node = blockIdx.x * 4 + (threadIdx.x >> 6);
    if (node >= N) return;
    int lane = threadIdx.x & 63;
    int q = lane >> 4, c = lane & 15;
    int beg = row_ptr[node], end = row_ptr[node + 1];
    float acc = 0.f;
    for (int e = beg + q; e < end; e += 4)
        acc += hs2[(size_t)csr[e] * N_CLS + c];
    acc += __shfl_xor(acc, 16, 64);
    acc += __shfl_xor(acc, 32, 64);
    float self = hs2[(size_t)node * N_CLS + c];
    float v = dinv[node] * (acc + self) + b2[c];
    float m = v;
#pragma unroll
    for (int off = 1; off < 16; off <<= 1) m = fmaxf(m, __shfl_xor(m, off, 64));
    float ex = __expf(v - m);
    float s = ex;
#pragma unroll
    for (int off = 1; off < 16; off <<= 1) s += __shfl_xor(s, off, 64);
    if (q == 0) out[(size_t)node * N_CLS + c] = v - m - __logf(s);
}

// ---------------- launch ----------------
extern "C" void kernel_launch(void* const* d_in, const int* in_sizes, int n_in,
                              void* d_out, int out_size, void* d_ws, size_t ws_size,
                              hipStream_t stream) {
    const float* x  = (const float*)d_in[0];
    const void* edges = d_in[1];
    const float* W1 = (const float*)d_in[2];
    const float* b1 = (const float*)d_in[3];
    const float* W2 = (const float*)d_in[4];
    const float* b2 = (const float*)d_in[5];
    float* out = (float*)d_out;

    const int N = in_sizes[0] / F_IN;   // 100000
    const int E = in_sizes[1] / 2;      // 3200000

    char* w = (char*)d_ws;
    size_t off = 0;
    auto take = [&](size_t bytes) {
        size_t o = off;
        off += (bytes + 15) & ~(size_t)15;
        return o;
    };
    float* hs1   = (float*)(w + take((size_t)N * F_HID * 4));
    float* out1  = (float*)(w + take((size_t)N * F_HID * 4));
    float* dinv  = (float*)(w + take((size_t)N * 4));
    int* counts  = (int*)(w + take((size_t)N * 4));
    int* cursor  = (int*)(w + take((size_t)N * 4));
    int* row_ptr = (int*)(w + take(((size_t)N + 1) * 4));
    int* bsums   = (int*)(w + take(512));
    int* flag    = (int*)(w + take(16));
    int* csr     = (int*)(w + take((size_t)E * 4));
    float* hs2   = hs1;  // hs1 dead after gather1 -> reuse for layer 2

    const int NB = (N + 1023) / 1024;  // scan blocks (<=128)
    const int FB = (E + FILL_K * 256 - 1) / (FILL_K * 256);  // fill blocks

    hipLaunchKernelGGL(k_detect, dim3(1), dim3(64), 0, stream, (const int*)edges, flag);
    hipMemsetAsync(counts, 0, (size_t)N * 4, stream);
    hipMemsetAsync(cursor, 0, (size_t)N * 4, stream);
    hipLaunchKernelGGL(k_hist, dim3(1024), dim3(256), 0, stream, edges, flag, counts, E);
    hipLaunchKernelGGL(k_dinv, dim3((N + 255) / 256), dim3(256), 0, stream, counts, dinv, N);
    hipLaunchKernelGGL(k_scan1, dim3(NB), dim3(256), 0, stream, counts, bsums, N);
    hipLaunchKernelGGL(k_scan2, dim3(1), dim3(128), 0, stream, bsums, NB);
    hipLaunchKernelGGL(k_scan3, dim3(NB), dim3(256), 0, stream, counts, bsums, row_ptr, N, E);
    hipLaunchKernelGGL(k_fill, dim3(FB), dim3(256), 0, stream, edges, flag, row_ptr, cursor, csr, E, N);
    hipLaunchKernelGGL(k_gemm1, dim3((N + 63) / 64), dim3(256), 0, stream, x, W1, dinv, hs1, N);
    hipLaunchKernelGGL(k_gather1, dim3((N + 3) / 4), dim3(256), 0, stream, hs1, csr, row_ptr, dinv, b1, out1, N);
    hipLaunchKernelGGL(k_gemm2, dim3((N + 255) / 256), dim3(256), 0, stream, out1, W2, dinv, hs2, N);
    hipLaunchKernelGGL(k_gather2, dim3((N + 3) / 4), dim3(256), 0, stream, hs2, csr, row_ptr, dinv, b2, out, N);
}

// Round 4
// 622.448 us; speedup vs baseline: 1.2796x; 1.2796x over previous
//
#include <hip/hip_runtime.h>
#include <cstdint>
#include <cstddef>

#define F_IN 512
#define F_HID 32
#define N_CLS 16

// ---------------- edge dtype detection (int32 vs int64) ----------------
__global__ void k_detect(const int* e, int* flag) {
    if (threadIdx.x == 0 && blockIdx.x == 0) {
        int zeros = 0;
        for (int i = 0; i < 1024; ++i) if (e[2 * i + 1] == 0) zeros++;
        *flag = (zeros >= 1016) ? 1 : 0;
    }
}

__device__ __forceinline__ int edge_get(const void* e, int is64, long long idx) {
    return is64 ? (int)((const long long*)e)[idx] : ((const int*)e)[idx];
}

// ---------------- degree histogram ----------------
__global__ void k_hist(const void* edges, const int* flag, int* counts, int E) {
    int is64 = *flag;
    long long i = (long long)blockIdx.x * blockDim.x + threadIdx.x;
    long long step = (long long)gridDim.x * blockDim.x;
    for (; i < E; i += step) {
        int d = edge_get(edges, is64, (long long)E + i);
        atomicAdd(&counts[d], 1);
    }
}

// ---------------- dinv = rsqrt(deg+1) ----------------
__global__ void k_dinv(const int* counts, float* dinv, int n) {
    int i = blockIdx.x * blockDim.x + threadIdx.x;
    if (i < n) dinv[i] = rsqrtf((float)counts[i] + 1.0f);
}

// ---------------- 3-kernel exclusive scan (chunk = 1024/block) ----------------
__global__ void k_scan1(const int* counts, int* bsums, int n) {
    int base = blockIdx.x * 1024;
    int t = threadIdx.x;
    int s = 0;
#pragma unroll
    for (int j = 0; j < 4; ++j) {
        int i = base + t * 4 + j;
        if (i < n) s += counts[i];
    }
#pragma unroll
    for (int off = 32; off; off >>= 1) s += __shfl_down(s, off, 64);
    __shared__ int ws[4];
    if ((t & 63) == 0) ws[t >> 6] = s;
    __syncthreads();
    if (t == 0) bsums[blockIdx.x] = ws[0] + ws[1] + ws[2] + ws[3];
}

__global__ void k_scan2(int* bsums, int nb) {  // single block, 128 threads, nb<=128
    __shared__ int tmp[128];
    int t = threadIdx.x;
    int v = (t < nb) ? bsums[t] : 0;
    tmp[t] = v;
    __syncthreads();
    for (int off = 1; off < 128; off <<= 1) {
        int add = (t >= off) ? tmp[t - off] : 0;
        __syncthreads();
        tmp[t] += add;
        __syncthreads();
    }
    if (t < nb) bsums[t] = tmp[t] - v;  // exclusive
}

__global__ void k_scan3(const int* counts, const int* bsums, int* row_ptr, int n, int E) {
    int base = blockIdx.x * 1024;
    int t = threadIdx.x, lane = t & 63, wid = t >> 6;
    int c[4];
    int tsum = 0;
#pragma unroll
    for (int j = 0; j < 4; ++j) {
        int i = base + t * 4 + j;
        c[j] = (i < n) ? counts[i] : 0;
        tsum += c[j];
    }
    int incl = tsum;
#pragma unroll
    for (int off = 1; off < 64; off <<= 1) {
        int u = __shfl_up(incl, off, 64);
        if (lane >= off) incl += u;
    }
    __shared__ int ws[4];
    if (lane == 63) ws[wid] = incl;
    __syncthreads();
    int woff = 0;
#pragma unroll
    for (int wv = 0; wv < 4; ++wv)
        if (wv < wid) woff += ws[wv];
    int excl = incl - tsum + woff + bsums[blockIdx.x];
#pragma unroll
    for (int j = 0; j < 4; ++j) {
        int i = base + t * 4 + j;
        if (i < n) row_ptr[i] = excl;
        excl += c[j];
    }
    if (blockIdx.x == 0 && t == 0) row_ptr[n] = E;
}

// ---------------- CSR fill (simple scatter; radix rework is a future round) ------
__global__ void k_fill(const void* edges, const int* flag, const int* row_ptr,
                       int* cursor, int* csr, int E) {
    int is64 = *flag;
    long long i = (long long)blockIdx.x * blockDim.x + threadIdx.x;
    long long step = (long long)gridDim.x * blockDim.x;
    for (; i < E; i += step) {
        int s = edge_get(edges, is64, i);
        int d = edge_get(edges, is64, (long long)E + i);
        int p = row_ptr[d] + atomicAdd(&cursor[d], 1);
        csr[p] = s;
    }
}

// ---------------- GEMM1: hs1 = (x @ W1) * dinv[row]  [N,512]x[512,32] ----------------
// Standard LDS-tiled GEMM: tile M=64 x N=32, K-chunks of 64. Thread owns 1 row x 8 cols.
// LDS ~25.7 KB -> 6 blocks/CU = 24 waves/CU. No scalar-W loads (round-3 spill lesson).
__global__ __launch_bounds__(256) void k_gemm1(const float* __restrict__ x,
                                               const float* __restrict__ W,
                                               const float* __restrict__ dinv,
                                               float* __restrict__ hs1, int N) {
    __shared__ float xs[64][68];   // 68 stride: 16B-aligned f4 writes, <=2-way read conflict
    __shared__ float Ws[64][32];
    int t = threadIdx.x;
    int row0 = blockIdx.x * 64;
    int r = t >> 2;            // 0..63
    int c0 = (t & 3) * 8;      // 0,8,16,24

    float acc[8];
#pragma unroll
    for (int j = 0; j < 8; ++j) acc[j] = 0.f;

    for (int kc = 0; kc < 8; ++kc) {
        // stage x chunk [64 rows][64 k] = 1024 f4; thread handles 4 (coalesced)
#pragma unroll
        for (int j = 0; j < 4; ++j) {
            int i = t + j * 256;
            int rr = i >> 4, kk = i & 15;
            int grow = row0 + rr;
            if (grow >= N) grow = N - 1;
            float4 v = *(const float4*)(x + (size_t)grow * F_IN + kc * 64 + kk * 4);
            *(float4*)(&xs[rr][kk * 4]) = v;
        }
        // stage W chunk [64 k][32 c] = 512 f4; thread handles 2
#pragma unroll
        for (int j = 0; j < 2; ++j) {
            int i = t + j * 256;
            int kk = i >> 3, cc = i & 7;
            float4 v = *(const float4*)(W + (size_t)(kc * 64 + kk) * F_HID + cc * 4);
            *(float4*)(&Ws[kk][cc * 4]) = v;
        }
        __syncthreads();
#pragma unroll
        for (int k = 0; k < 64; ++k) {
            float xv = xs[r][k];
#pragma unroll
            for (int j = 0; j < 8; ++j)
                acc[j] = fmaf(xv, Ws[k][c0 + j], acc[j]);
        }
        __syncthreads();
    }
    int grow = row0 + r;
    if (grow < N) {
        float di = dinv[grow];
        float* o = hs1 + (size_t)grow * F_HID + c0;
        *(float4*)(o)     = make_float4(acc[0] * di, acc[1] * di, acc[2] * di, acc[3] * di);
        *(float4*)(o + 4) = make_float4(acc[4] * di, acc[5] * di, acc[6] * di, acc[7] * di);
    }
}

// ---------------- gather layer 1: out1 = relu(dinv*(hs1_self + sum hs1[src]) + b1) ----
__global__ __launch_bounds__(256) void k_gather1(const float* __restrict__ hs1,
                                                 const int* __restrict__ csr,
                                                 const int* __restrict__ row_ptr,
                                                 const float* __restrict__ dinv,
                                                 const float* __restrict__ b1,
                                                 float* __restrict__ out1, int N) {
    int node = blockIdx.x * 4 + (threadIdx.x >> 6);
    if (node >= N) return;
    int lane = threadIdx.x & 63;
    int half = lane >> 5, c = lane & 31;
    int beg = row_ptr[node], end = row_ptr[node + 1];
    float a0 = 0.f, a1 = 0.f;
    int e = beg + half;
    while (e + 2 < end) {
        int s0 = csr[e], s1 = csr[e + 2];
        a0 += hs1[(size_t)s0 * F_HID + c];
        a1 += hs1[(size_t)s1 * F_HID + c];
        e += 4;
    }
    if (e < end) a0 += hs1[(size_t)csr[e] * F_HID + c];
    float acc = a0 + a1;
    acc += __shfl_xor(acc, 32, 64);
    float self = hs1[(size_t)node * F_HID + c];
    float v = dinv[node] * (acc + self) + b1[c];
    v = fmaxf(v, 0.f);
    if (half == 0) out1[(size_t)node * F_HID + c] = v;
}

// ---------------- GEMM2: hs2 = (out1 @ W2) * dinv  [N,32]x[32,16] ----------------
__global__ __launch_bounds__(256) void k_gemm2(const float* __restrict__ in,
                                               const float* __restrict__ W,
                                               const float* __restrict__ dinv,
                                               float* __restrict__ hs2, int N) {
    int row = blockIdx.x * 256 + threadIdx.x;
    if (row >= N) return;
    const float4* xr = (const float4*)(in + (size_t)row * F_HID);
    float acc[16];
#pragma unroll
    for (int c = 0; c < 16; ++c) acc[c] = 0.f;
#pragma unroll
    for (int k4 = 0; k4 < 8; ++k4) {
        float4 xv = xr[k4];
        const float* wr = W + k4 * 64;
#pragma unroll
        for (int c = 0; c < 16; ++c) {
            acc[c] = fmaf(xv.x, wr[c], acc[c]);
            acc[c] = fmaf(xv.y, wr[16 + c], acc[c]);
            acc[c] = fmaf(xv.z, wr[32 + c], acc[c]);
            acc[c] = fmaf(xv.w, wr[48 + c], acc[c]);
        }
    }
    float di = dinv[row];
    float* o = hs2 + (size_t)row * N_CLS;
#pragma unroll
    for (int c = 0; c < 16; c += 4) {
        float4 v = make_float4(acc[c] * di, acc[c + 1] * di, acc[c + 2] * di, acc[c + 3] * di);
        *(float4*)(o + c) = v;
    }
}

// ---------------- gather layer 2 + bias + log_softmax ----------------
__global__ __launch_bounds__(256) void k_gather2(const float* __restrict__ hs2,
                                                 const int* __restrict__ csr,
                                                 const int* __restrict__ row_ptr,
                                                 const float* __restrict__ dinv,
                                                 const float* __restrict__ b2,
                                                 float* __restrict__ out, int N) {
    int node = blockIdx.x * 4 + (threadIdx.x >> 6);
    if (node >= N) return;
    int lane = threadIdx.x & 63;
    int q = lane >> 4, c = lane & 15;
    int beg = row_ptr[node], end = row_ptr[node + 1];
    float acc = 0.f;
    for (int e = beg + q; e < end; e += 4)
        acc += hs2[(size_t)csr[e] * N_CLS + c];
    acc += __shfl_xor(acc, 16, 64);
    acc += __shfl_xor(acc, 32, 64);
    float self = hs2[(size_t)node * N_CLS + c];
    float v = dinv[node] * (acc + self) + b2[c];
    float m = v;
#pragma unroll
    for (int off = 1; off < 16; off <<= 1) m = fmaxf(m, __shfl_xor(m, off, 64));
    float ex = __expf(v - m);
    float s = ex;
#pragma unroll
    for (int off = 1; off < 16; off <<= 1) s += __shfl_xor(s, off, 64);
    if (q == 0) out[(size_t)node * N_CLS + c] = v - m - __logf(s);
}

// ---------------- launch ----------------
extern "C" void kernel_launch(void* const* d_in, const int* in_sizes, int n_in,
                              void* d_out, int out_size, void* d_ws, size_t ws_size,
                              hipStream_t stream) {
    const float* x  = (const float*)d_in[0];
    const void* edges = d_in[1];
    const float* W1 = (const float*)d_in[2];
    const float* b1 = (const float*)d_in[3];
    const float* W2 = (const float*)d_in[4];
    const float* b2 = (const float*)d_in[5];
    float* out = (float*)d_out;

    const int N = in_sizes[0] / F_IN;   // 100000
    const int E = in_sizes[1] / 2;      // 3200000

    char* w = (char*)d_ws;
    size_t off = 0;
    auto take = [&](size_t bytes) {
        size_t o = off;
        off += (bytes + 15) & ~(size_t)15;
        return o;
    };
    float* hs1   = (float*)(w + take((size_t)N * F_HID * 4));
    float* out1  = (float*)(w + take((size_t)N * F_HID * 4));
    float* dinv  = (float*)(w + take((size_t)N * 4));
    int* counts  = (int*)(w + take((size_t)N * 4));
    int* cursor  = (int*)(w + take((size_t)N * 4));
    int* row_ptr = (int*)(w + take(((size_t)N + 1) * 4));
    int* bsums   = (int*)(w + take(512));
    int* flag    = (int*)(w + take(16));
    int* csr     = (int*)(w + take((size_t)E * 4));
    float* hs2   = hs1;  // hs1 dead after gather1 -> reuse for layer 2

    const int NB = (N + 1023) / 1024;  // scan blocks (<=128)

    hipLaunchKernelGGL(k_detect, dim3(1), dim3(64), 0, stream, (const int*)edges, flag);
    hipMemsetAsync(counts, 0, (size_t)N * 4, stream);
    hipMemsetAsync(cursor, 0, (size_t)N * 4, stream);
    hipLaunchKernelGGL(k_hist, dim3(1024), dim3(256), 0, stream, edges, flag, counts, E);
    hipLaunchKernelGGL(k_dinv, dim3((N + 255) / 256), dim3(256), 0, stream, counts, dinv, N);
    hipLaunchKernelGGL(k_scan1, dim3(NB), dim3(256), 0, stream, counts, bsums, N);
    hipLaunchKernelGGL(k_scan2, dim3(1), dim3(128), 0, stream, bsums, NB);
    hipLaunchKernelGGL(k_scan3, dim3(NB), dim3(256), 0, stream, counts, bsums, row_ptr, N, E);
    hipLaunchKernelGGL(k_fill, dim3(1024), dim3(256), 0, stream, edges, flag, row_ptr, cursor, csr, E);
    hipLaunchKernelGGL(k_gemm1, dim3((N + 63) / 64), dim3(256), 0, stream, x, W1, dinv, hs1, N);
    hipLaunchKernelGGL(k_gather1, dim3((N + 3) / 4), dim3(256), 0, stream, hs1, csr, row_ptr, dinv, b1, out1, N);
    hipLaunchKernelGGL(k_gemm2, dim3((N + 255) / 256), dim3(256), 0, stream, out1, W2, dinv, hs2, N);
    hipLaunchKernelGGL(k_gather2, dim3((N + 3) / 4), dim3(256), 0, stream, hs2, csr, row_ptr, dinv, b2, out, N);
}

// Round 5
// 444.692 us; speedup vs baseline: 1.7910x; 1.3997x over previous
//
#include <hip/hip_runtime.h>
#include <cstdint>
#include <cstddef>

#define F_IN 512
#define F_HID 32
#define N_CLS 16
#define BSH 9                 // 512 nodes per bucket
#define BNODES (1 << BSH)

// ---------------- edge dtype detection (int32 vs int64) ----------------
__global__ void k_detect(const int* e, int* flag) {
    if (threadIdx.x == 0 && blockIdx.x == 0) {
        int zeros = 0;
        for (int i = 0; i < 1024; ++i) if (e[2 * i + 1] == 0) zeros++;
        *flag = (zeros >= 1016) ? 1 : 0;
    }
}

__device__ __forceinline__ int edge_get(const void* e, int is64, long long idx) {
    return is64 ? (int)((const long long*)e)[idx] : ((const int*)e)[idx];
}

// ---------------- bucket histogram (LDS-aggregated) ----------------
__global__ __launch_bounds__(256) void k_bcount(const void* edges, const int* flag,
                                                int* bcnt, int E, int nbuk) {
    __shared__ int h[256];
    int t = threadIdx.x;
    if (t < nbuk) h[t] = 0;
    __syncthreads();
    int is64 = *flag;
    long long i = (long long)blockIdx.x * blockDim.x + t;
    long long step = (long long)gridDim.x * blockDim.x;
    for (; i < E; i += step) {
        int d = edge_get(edges, is64, (long long)E + i);
        atomicAdd(&h[d >> BSH], 1);
    }
    __syncthreads();
    if (t < nbuk && h[t]) atomicAdd(&bcnt[t], h[t]);
}

// ---------------- bucket base scan (1 block) ----------------
__global__ void k_bscan(const int* bcnt, int* bbase, int* bcur, int nbuk, int E) {
    __shared__ int tmp[256];
    int t = threadIdx.x;
    int v = (t < nbuk) ? bcnt[t] : 0;
    tmp[t] = v;
    __syncthreads();
    for (int off = 1; off < 256; off <<= 1) {
        int a = (t >= off) ? tmp[t - off] : 0;
        __syncthreads();
        tmp[t] += a;
        __syncthreads();
    }
    int ex = tmp[t] - v;
    if (t < nbuk) { bbase[t] = ex; bcur[t] = ex; }
    if (t == 0) bbase[nbuk] = E;
}

// ---------------- bucket scatter: packed (dlocal<<17 | src) into bucket segments ----
#define SK 16
__global__ __launch_bounds__(256) void k_bscatter(const void* edges, const int* flag,
                                                  int* bcur, int* __restrict__ bucket,
                                                  int E, int nbuk) {
    __shared__ int h[256], sbase[256];
    int t = threadIdx.x;
    if (t < nbuk) h[t] = 0;
    __syncthreads();
    int is64 = *flag;
    long long base = (long long)blockIdx.x * 256 * SK;
    int ss[SK], dd[SK], rk[SK];
#pragma unroll
    for (int j = 0; j < SK; ++j) {
        long long i = base + j * 256 + t;
        if (i < E) {
            dd[j] = edge_get(edges, is64, (long long)E + i);
            ss[j] = edge_get(edges, is64, i);
            rk[j] = atomicAdd(&h[dd[j] >> BSH], 1);  // in-block rank
        } else dd[j] = -1;
    }
    __syncthreads();
    if (t < nbuk && h[t]) sbase[t] = atomicAdd(&bcur[t], h[t]);
    __syncthreads();
#pragma unroll
    for (int j = 0; j < SK; ++j) {
        if (dd[j] >= 0) {
            int b = dd[j] >> BSH;
            bucket[sbase[b] + rk[j]] = ((dd[j] & (BNODES - 1)) << 17) | ss[j];
        }
    }
}

// ---------------- per-bucket build: row_ptr + dinv + csr (no global atomics) -------
__global__ __launch_bounds__(512) void k_build(const int* __restrict__ bucket,
                                               const int* __restrict__ bbase,
                                               int* __restrict__ row_ptr,
                                               float* __restrict__ dinv,
                                               int* __restrict__ csr,
                                               int N, int nbuk, int E) {
    __shared__ int cnt[512];
    __shared__ int wsum[8];
    int b = blockIdx.x;
    int t = threadIdx.x;
    int nb0 = b << BSH;
    int beg = bbase[b], end = bbase[b + 1];
    cnt[t] = 0;
    __syncthreads();
    for (int e = beg + t; e < end; e += 512)
        atomicAdd(&cnt[bucket[e] >> 17], 1);
    __syncthreads();
    int v = cnt[t];
    // exclusive scan over 512 (wave shfl + wave sums)
    int lane = t & 63, w = t >> 6;
    int inc = v;
#pragma unroll
    for (int off = 1; off < 64; off <<= 1) {
        int u = __shfl_up(inc, off, 64);
        if (lane >= off) inc += u;
    }
    if (lane == 63) wsum[w] = inc;
    __syncthreads();
    int wo = 0;
#pragma unroll
    for (int k = 0; k < 8; ++k)
        if (k < w) wo += wsum[k];
    int excl = inc - v + wo;
    int node = nb0 + t;
    if (node < N) {
        row_ptr[node] = beg + excl;
        dinv[node] = rsqrtf((float)v + 1.0f);
    }
    __syncthreads();
    cnt[t] = beg + excl;  // becomes cursor
    __syncthreads();
    for (int e = beg + t; e < end; e += 512) {
        int p = bucket[e];
        int pos = atomicAdd(&cnt[p >> 17], 1);
        csr[pos] = p & 0x1FFFF;
    }
    if (b == nbuk - 1 && t == 0) row_ptr[N] = E;
}

// ---------------- GEMM1: hs1 = (x @ W1) * dinv[row]  [N,512]x[512,32] ----------------
__global__ __launch_bounds__(256) void k_gemm1(const float* __restrict__ x,
                                               const float* __restrict__ W,
                                               const float* __restrict__ dinv,
                                               float* __restrict__ hs1, int N) {
    __shared__ float xs[64][68];
    __shared__ float Ws[64][32];
    int t = threadIdx.x;
    int row0 = blockIdx.x * 64;
    int r = t >> 2;
    int c0 = (t & 3) * 8;

    float acc[8];
#pragma unroll
    for (int j = 0; j < 8; ++j) acc[j] = 0.f;

    for (int kc = 0; kc < 8; ++kc) {
#pragma unroll
        for (int j = 0; j < 4; ++j) {
            int i = t + j * 256;
            int rr = i >> 4, kk = i & 15;
            int grow = row0 + rr;
            if (grow >= N) grow = N - 1;
            float4 v = *(const float4*)(x + (size_t)grow * F_IN + kc * 64 + kk * 4);
            *(float4*)(&xs[rr][kk * 4]) = v;
        }
#pragma unroll
        for (int j = 0; j < 2; ++j) {
            int i = t + j * 256;
            int kk = i >> 3, cc = i & 7;
            float4 v = *(const float4*)(W + (size_t)(kc * 64 + kk) * F_HID + cc * 4);
            *(float4*)(&Ws[kk][cc * 4]) = v;
        }
        __syncthreads();
#pragma unroll
        for (int k = 0; k < 64; ++k) {
            float xv = xs[r][k];
#pragma unroll
            for (int j = 0; j < 8; ++j)
                acc[j] = fmaf(xv, Ws[k][c0 + j], acc[j]);
        }
        __syncthreads();
    }
    int grow = row0 + r;
    if (grow < N) {
        float di = dinv[grow];
        float* o = hs1 + (size_t)grow * F_HID + c0;
        *(float4*)(o)     = make_float4(acc[0] * di, acc[1] * di, acc[2] * di, acc[3] * di);
        *(float4*)(o + 4) = make_float4(acc[4] * di, acc[5] * di, acc[6] * di, acc[7] * di);
    }
}

// ---------------- gather layer 1: out1 = relu(dinv*(hs1_self + sum hs1[src]) + b1) ----
__global__ __launch_bounds__(256) void k_gather1(const float* __restrict__ hs1,
                                                 const int* __restrict__ csr,
                                                 const int* __restrict__ row_ptr,
                                                 const float* __restrict__ dinv,
                                                 const float* __restrict__ b1,
                                                 float* __restrict__ out1, int N) {
    int node = blockIdx.x * 4 + (threadIdx.x >> 6);
    if (node >= N) return;
    int lane = threadIdx.x & 63;
    int half = lane >> 5, c = lane & 31;
    int beg = row_ptr[node], end = row_ptr[node + 1];
    float a0 = 0.f, a1 = 0.f;
    int e = beg + half;
    while (e + 2 < end) {
        int s0 = csr[e], s1 = csr[e + 2];
        a0 += hs1[(size_t)s0 * F_HID + c];
        a1 += hs1[(size_t)s1 * F_HID + c];
        e += 4;
    }
    if (e < end) a0 += hs1[(size_t)csr[e] * F_HID + c];
    float acc = a0 + a1;
    acc += __shfl_xor(acc, 32, 64);
    float self = hs1[(size_t)node * F_HID + c];
    float v = dinv[node] * (acc + self) + b1[c];
    v = fmaxf(v, 0.f);
    if (half == 0) out1[(size_t)node * F_HID + c] = v;
}

// ---------------- GEMM2: hs2 = (out1 @ W2) * dinv  [N,32]x[32,16] ----------------
__global__ __launch_bounds__(256) void k_gemm2(const float* __restrict__ in,
                                               const float* __restrict__ W,
                                               const float* __restrict__ dinv,
                                               float* __restrict__ hs2, int N) {
    int row = blockIdx.x * 256 + threadIdx.x;
    if (row >= N) return;
    const float4* xr = (const float4*)(in + (size_t)row * F_HID);
    float acc[16];
#pragma unroll
    for (int c = 0; c < 16; ++c) acc[c] = 0.f;
#pragma unroll
    for (int k4 = 0; k4 < 8; ++k4) {
        float4 xv = xr[k4];
        const float* wr = W + k4 * 64;
#pragma unroll
        for (int c = 0; c < 16; ++c) {
            acc[c] = fmaf(xv.x, wr[c], acc[c]);
            acc[c] = fmaf(xv.y, wr[16 + c], acc[c]);
            acc[c] = fmaf(xv.z, wr[32 + c], acc[c]);
            acc[c] = fmaf(xv.w, wr[48 + c], acc[c]);
        }
    }
    float di = dinv[row];
    float* o = hs2 + (size_t)row * N_CLS;
#pragma unroll
    for (int c = 0; c < 16; c += 4) {
        float4 v = make_float4(acc[c] * di, acc[c + 1] * di, acc[c + 2] * di, acc[c + 3] * di);
        *(float4*)(o + c) = v;
    }
}

// ---------------- gather layer 2 + bias + log_softmax ----------------
__global__ __launch_bounds__(256) void k_gather2(const float* __restrict__ hs2,
                                                 const int* __restrict__ csr,
                                                 const int* __restrict__ row_ptr,
                                                 const float* __restrict__ dinv,
                                                 const float* __restrict__ b2,
                                                 float* __restrict__ out, int N) {
    int node = blockIdx.x * 4 + (threadIdx.x >> 6);
    if (node >= N) return;
    int lane = threadIdx.x & 63;
    int q = lane >> 4, c = lane & 15;
    int beg = row_ptr[node], end = row_ptr[node + 1];
    float acc = 0.f;
    for (int e = beg + q; e < end; e += 4)
        acc += hs2[(size_t)csr[e] * N_CLS + c];
    acc += __shfl_xor(acc, 16, 64);
    acc += __shfl_xor(acc, 32, 64);
    float self = hs2[(size_t)node * N_CLS + c];
    float v = dinv[node] * (acc + self) + b2[c];
    float m = v;
#pragma unroll
    for (int off = 1; off < 16; off <<= 1) m = fmaxf(m, __shfl_xor(m, off, 64));
    float ex = __expf(v - m);
    float s = ex;
#pragma unroll
    for (int off = 1; off < 16; off <<= 1) s += __shfl_xor(s, off, 64);
    if (q == 0) out[(size_t)node * N_CLS + c] = v - m - __logf(s);
}

// ---------------- launch ----------------
extern "C" void kernel_launch(void* const* d_in, const int* in_sizes, int n_in,
                              void* d_out, int out_size, void* d_ws, size_t ws_size,
                              hipStream_t stream) {
    const float* x  = (const float*)d_in[0];
    const void* edges = d_in[1];
    const float* W1 = (const float*)d_in[2];
    const float* b1 = (const float*)d_in[3];
    const float* W2 = (const float*)d_in[4];
    const float* b2 = (const float*)d_in[5];
    float* out = (float*)d_out;

    const int N = in_sizes[0] / F_IN;   // 100000 (packing requires N < 131072)
    const int E = in_sizes[1] / 2;      // 3200000
    const int NBUK = (N + BNODES - 1) >> BSH;  // 196

    char* w = (char*)d_ws;
    size_t off = 0;
    auto take = [&](size_t bytes) {
        size_t o = off;
        off += (bytes + 15) & ~(size_t)15;
        return o;
    };
    float* hs1    = (float*)(w + take((size_t)N * F_HID * 4));
    float* out1   = (float*)(w + take((size_t)N * F_HID * 4));
    float* dinv   = (float*)(w + take((size_t)N * 4));
    int* row_ptr  = (int*)(w + take(((size_t)N + 1) * 4));
    int* bucket   = (int*)(w + take((size_t)E * 4));
    int* csr      = (int*)(w + take((size_t)E * 4));
    int* bcnt     = (int*)(w + take(1024));
    int* bbase    = (int*)(w + take(1040));
    int* bcur     = (int*)(w + take(1024));
    int* flag     = (int*)(w + take(16));
    float* hs2    = hs1;  // hs1 dead after gather1 -> reuse

    hipLaunchKernelGGL(k_detect, dim3(1), dim3(64), 0, stream, (const int*)edges, flag);
    hipMemsetAsync(bcnt, 0, 1024, stream);
    hipLaunchKernelGGL(k_bcount, dim3(512), dim3(256), 0, stream, edges, flag, bcnt, E, NBUK);
    hipLaunchKernelGGL(k_bscan, dim3(1), dim3(256), 0, stream, bcnt, bbase, bcur, NBUK, E);
    const int SB = (E + 256 * SK - 1) / (256 * SK);
    hipLaunchKernelGGL(k_bscatter, dim3(SB), dim3(256), 0, stream, edges, flag, bcur, bucket, E, NBUK);
    hipLaunchKernelGGL(k_build, dim3(NBUK), dim3(512), 0, stream, bucket, bbase, row_ptr, dinv, csr, N, NBUK, E);
    hipLaunchKernelGGL(k_gemm1, dim3((N + 63) / 64), dim3(256), 0, stream, x, W1, dinv, hs1, N);
    hipLaunchKernelGGL(k_gather1, dim3((N + 3) / 4), dim3(256), 0, stream, hs1, csr, row_ptr, dinv, b1, out1, N);
    hipLaunchKernelGGL(k_gemm2, dim3((N + 255) / 256), dim3(256), 0, stream, out1, W2, dinv, hs2, N);
    hipLaunchKernelGGL(k_gather2, dim3((N + 3) / 4), dim3(256), 0, stream, hs2, csr, row_ptr, dinv, b2, out, N);
}

// Round 6
// 287.477 us; speedup vs baseline: 2.7705x; 1.5469x over previous
//
#include <hip/hip_runtime.h>
#include <cstdint>
#include <cstddef>

#define F_IN 512
#define F_HID 32
#define N_CLS 16
#define BSH 9                 // 512 nodes per bucket
#define BNODES (1 << BSH)

__device__ __forceinline__ float4 shfl_xor_f4(float4 v, int mask) {
    v.x = __shfl_xor(v.x, mask, 64);
    v.y = __shfl_xor(v.y, mask, 64);
    v.z = __shfl_xor(v.z, mask, 64);
    v.w = __shfl_xor(v.w, mask, 64);
    return v;
}

// ---------------- edge dtype detection (int32 vs int64) + bcnt zero ----------------
__global__ __launch_bounds__(256) void k_detect(const int* e, int* flag, int* bcnt) {
    __shared__ int zc;
    int t = threadIdx.x;
    if (t == 0) zc = 0;
    __syncthreads();
    int z = 0;
#pragma unroll
    for (int j = 0; j < 4; ++j)
        if (e[2 * (t * 4 + j) + 1] == 0) z++;
    if (z) atomicAdd(&zc, z);
    bcnt[t] = 0;
    __syncthreads();
    if (t == 0) *flag = (zc >= 1016) ? 1 : 0;
}

__device__ __forceinline__ int edge_get(const void* e, int is64, long long idx) {
    return is64 ? (int)((const long long*)e)[idx] : ((const int*)e)[idx];
}

// ---------------- bucket histogram (LDS-aggregated) ----------------
__global__ __launch_bounds__(256) void k_bcount(const void* edges, const int* flag,
                                                int* bcnt, int E, int nbuk) {
    __shared__ int h[256];
    int t = threadIdx.x;
    if (t < nbuk) h[t] = 0;
    __syncthreads();
    int is64 = *flag;
    long long i = (long long)blockIdx.x * blockDim.x + t;
    long long step = (long long)gridDim.x * blockDim.x;
    for (; i < E; i += step) {
        int d = edge_get(edges, is64, (long long)E + i);
        atomicAdd(&h[d >> BSH], 1);
    }
    __syncthreads();
    if (t < nbuk && h[t]) atomicAdd(&bcnt[t], h[t]);
}

// ---------------- bucket base scan (1 block) ----------------
__global__ void k_bscan(const int* bcnt, int* bbase, int* bcur, int nbuk, int E) {
    __shared__ int tmp[256];
    int t = threadIdx.x;
    int v = (t < nbuk) ? bcnt[t] : 0;
    tmp[t] = v;
    __syncthreads();
    for (int off = 1; off < 256; off <<= 1) {
        int a = (t >= off) ? tmp[t - off] : 0;
        __syncthreads();
        tmp[t] += a;
        __syncthreads();
    }
    int ex = tmp[t] - v;
    if (t < nbuk) { bbase[t] = ex; bcur[t] = ex; }
    if (t == 0) bbase[nbuk] = E;
}

// ---------------- bucket scatter: packed (dlocal<<17 | src) into bucket segments ----
#define SK 16
__global__ __launch_bounds__(256) void k_bscatter(const void* edges, const int* flag,
                                                  int* bcur, int* __restrict__ bucket,
                                                  int E, int nbuk) {
    __shared__ int h[256], sbase[256];
    int t = threadIdx.x;
    if (t < nbuk) h[t] = 0;
    __syncthreads();
    int is64 = *flag;
    long long base = (long long)blockIdx.x * 256 * SK;
    int ss[SK], dd[SK], rk[SK];
#pragma unroll
    for (int j = 0; j < SK; ++j) {
        long long i = base + j * 256 + t;
        if (i < E) {
            dd[j] = edge_get(edges, is64, (long long)E + i);
            ss[j] = edge_get(edges, is64, i);
            rk[j] = atomicAdd(&h[dd[j] >> BSH], 1);  // in-block rank
        } else dd[j] = -1;
    }
    __syncthreads();
    if (t < nbuk && h[t]) sbase[t] = atomicAdd(&bcur[t], h[t]);
    __syncthreads();
#pragma unroll
    for (int j = 0; j < SK; ++j) {
        if (dd[j] >= 0) {
            int b = dd[j] >> BSH;
            bucket[sbase[b] + rk[j]] = ((dd[j] & (BNODES - 1)) << 17) | ss[j];
        }
    }
}

// ---------------- per-bucket build: row_ptr + dinv + csr (no global atomics) -------
__global__ __launch_bounds__(512) void k_build(const int* __restrict__ bucket,
                                               const int* __restrict__ bbase,
                                               int* __restrict__ row_ptr,
                                               float* __restrict__ dinv,
                                               int* __restrict__ csr,
                                               int N, int nbuk, int E) {
    __shared__ int cnt[512];
    __shared__ int wsum[8];
    int b = blockIdx.x;
    int t = threadIdx.x;
    int nb0 = b << BSH;
    int beg = bbase[b], end = bbase[b + 1];
    cnt[t] = 0;
    __syncthreads();
    for (int e = beg + t; e < end; e += 512)
        atomicAdd(&cnt[bucket[e] >> 17], 1);
    __syncthreads();
    int v = cnt[t];
    int lane = t & 63, w = t >> 6;
    int inc = v;
#pragma unroll
    for (int off = 1; off < 64; off <<= 1) {
        int u = __shfl_up(inc, off, 64);
        if (lane >= off) inc += u;
    }
    if (lane == 63) wsum[w] = inc;
    __syncthreads();
    int wo = 0;
#pragma unroll
    for (int k = 0; k < 8; ++k)
        if (k < w) wo += wsum[k];
    int excl = inc - v + wo;
    int node = nb0 + t;
    if (node < N) {
        row_ptr[node] = beg + excl;
        dinv[node] = rsqrtf((float)v + 1.0f);
    }
    __syncthreads();
    cnt[t] = beg + excl;  // becomes cursor
    __syncthreads();
    for (int e = beg + t; e < end; e += 512) {
        int p = bucket[e];
        int pos = atomicAdd(&cnt[p >> 17], 1);
        csr[pos] = p & 0x1FFFF;
    }
    if (b == nbuk - 1 && t == 0) row_ptr[N] = E;
}

// ---------------- GEMM1: hs1 = (x @ W1) * dinv[row]  [N,512]x[512,32] ----------------
// M=128 tile, thread owns rows (r0, r0+64) x 8 cols: per-k 2 b32 + 2 b128 feed 32
// FMA-cycles (balanced). Row split keeps xs column reads at free 2-way aliasing.
__global__ __launch_bounds__(256) void k_gemm1(const float* __restrict__ x,
                                               const float* __restrict__ W,
                                               const float* __restrict__ dinv,
                                               float* __restrict__ hs1, int N) {
    __shared__ float xs[128][68];
    __shared__ float Ws[64][32];
    int t = threadIdx.x;
    int row0 = blockIdx.x * 128;
    int r0 = t >> 2;           // 0..63
    int c0 = (t & 3) * 8;      // 0,8,16,24

    float acc0[8], acc1[8];
#pragma unroll
    for (int j = 0; j < 8; ++j) { acc0[j] = 0.f; acc1[j] = 0.f; }

    for (int kc = 0; kc < 8; ++kc) {
        // stage x chunk [128 rows][64 k] = 2048 f4, 8 per thread
#pragma unroll
        for (int j = 0; j < 8; ++j) {
            int i = t + j * 256;
            int rr = i >> 4, kk = i & 15;
            int grow = row0 + rr;
            if (grow >= N) grow = N - 1;
            *(float4*)(&xs[rr][kk * 4]) =
                *(const float4*)(x + (size_t)grow * F_IN + kc * 64 + kk * 4);
        }
        // stage W chunk [64 k][32 c] = 512 f4, 2 per thread
#pragma unroll
        for (int j = 0; j < 2; ++j) {
            int i = t + j * 256;
            int kk = i >> 3, cc = i & 7;
            *(float4*)(&Ws[kk][cc * 4]) =
                *(const float4*)(W + (size_t)(kc * 64 + kk) * F_HID + cc * 4);
        }
        __syncthreads();
#pragma unroll 8
        for (int k = 0; k < 64; ++k) {
            float x0 = xs[r0][k];
            float x1 = xs[r0 + 64][k];
#pragma unroll
            for (int j = 0; j < 8; ++j) {
                float wv = Ws[k][c0 + j];
                acc0[j] = fmaf(x0, wv, acc0[j]);
                acc1[j] = fmaf(x1, wv, acc1[j]);
            }
        }
        __syncthreads();
    }
    int g0 = row0 + r0, g1 = row0 + r0 + 64;
    if (g0 < N) {
        float di = dinv[g0];
        float* o = hs1 + (size_t)g0 * F_HID + c0;
        *(float4*)(o)     = make_float4(acc0[0] * di, acc0[1] * di, acc0[2] * di, acc0[3] * di);
        *(float4*)(o + 4) = make_float4(acc0[4] * di, acc0[5] * di, acc0[6] * di, acc0[7] * di);
    }
    if (g1 < N) {
        float di = dinv[g1];
        float* o = hs1 + (size_t)g1 * F_HID + c0;
        *(float4*)(o)     = make_float4(acc1[0] * di, acc1[1] * di, acc1[2] * di, acc1[3] * di);
        *(float4*)(o + 4) = make_float4(acc1[4] * di, acc1[5] * di, acc1[6] * di, acc1[7] * di);
    }
}

// ---------------- gather layer 1: 8 lanes/edge x float4, 8 edges in flight ---------
__global__ __launch_bounds__(256) void k_gather1(const float* __restrict__ hs1,
                                                 const int* __restrict__ csr,
                                                 const int* __restrict__ row_ptr,
                                                 const float* __restrict__ dinv,
                                                 const float* __restrict__ b1,
                                                 float* __restrict__ out1, int N) {
    int node = blockIdx.x * 4 + (threadIdx.x >> 6);
    if (node >= N) return;
    int lane = threadIdx.x & 63;
    int g = lane >> 3, l = lane & 7;      // edge-slot, f4-index
    const float4* h4 = (const float4*)hs1;
    int beg = row_ptr[node], end = row_ptr[node + 1];
    float4 a = make_float4(0.f, 0.f, 0.f, 0.f);
    for (int e = beg + g; e < end; e += 8) {
        int src = csr[e];
        float4 v = h4[(size_t)src * 8 + l];
        a.x += v.x; a.y += v.y; a.z += v.z; a.w += v.w;
    }
    float4 u;
    u = shfl_xor_f4(a, 8);  a.x += u.x; a.y += u.y; a.z += u.z; a.w += u.w;
    u = shfl_xor_f4(a, 16); a.x += u.x; a.y += u.y; a.z += u.z; a.w += u.w;
    u = shfl_xor_f4(a, 32); a.x += u.x; a.y += u.y; a.z += u.z; a.w += u.w;
    if (g == 0) {
        float4 self = h4[(size_t)node * 8 + l];
        float di = dinv[node];
        float4 bb = ((const float4*)b1)[l];
        float4 r;
        r.x = fmaxf(di * (a.x + self.x) + bb.x, 0.f);
        r.y = fmaxf(di * (a.y + self.y) + bb.y, 0.f);
        r.z = fmaxf(di * (a.z + self.z) + bb.z, 0.f);
        r.w = fmaxf(di * (a.w + self.w) + bb.w, 0.f);
        ((float4*)out1)[(size_t)node * 8 + l] = r;
    }
}

// ---------------- GEMM2: hs2 = (out1 @ W2) * dinv  [N,32]x[32,16] ----------------
__global__ __launch_bounds__(256) void k_gemm2(const float* __restrict__ in,
                                               const float* __restrict__ W,
                                               const float* __restrict__ dinv,
                                               float* __restrict__ hs2, int N) {
    int row = blockIdx.x * 256 + threadIdx.x;
    if (row >= N) return;
    const float4* xr = (const float4*)(in + (size_t)row * F_HID);
    float acc[16];
#pragma unroll
    for (int c = 0; c < 16; ++c) acc[c] = 0.f;
#pragma unroll
    for (int k4 = 0; k4 < 8; ++k4) {
        float4 xv = xr[k4];
        const float* wr = W + k4 * 64;
#pragma unroll
        for (int c = 0; c < 16; ++c) {
            acc[c] = fmaf(xv.x, wr[c], acc[c]);
            acc[c] = fmaf(xv.y, wr[16 + c], acc[c]);
            acc[c] = fmaf(xv.z, wr[32 + c], acc[c]);
            acc[c] = fmaf(xv.w, wr[48 + c], acc[c]);
        }
    }
    float di = dinv[row];
    float* o = hs2 + (size_t)row * N_CLS;
#pragma unroll
    for (int c = 0; c < 16; c += 4) {
        float4 v = make_float4(acc[c] * di, acc[c + 1] * di, acc[c + 2] * di, acc[c + 3] * di);
        *(float4*)(o + c) = v;
    }
}

// ---------------- gather layer 2: 4 lanes/edge x float4, 16 edges in flight + softmax
__global__ __launch_bounds__(256) void k_gather2(const float* __restrict__ hs2,
                                                 const int* __restrict__ csr,
                                                 const int* __restrict__ row_ptr,
                                                 const float* __restrict__ dinv,
                                                 const float* __restrict__ b2,
                                                 float* __restrict__ out, int N) {
    int node = blockIdx.x * 4 + (threadIdx.x >> 6);
    if (node >= N) return;
    int lane = threadIdx.x & 63;
    int g = lane >> 2, l = lane & 3;
    const float4* h4 = (const float4*)hs2;
    int beg = row_ptr[node], end = row_ptr[node + 1];
    float4 a = make_float4(0.f, 0.f, 0.f, 0.f);
    for (int e = beg + g; e < end; e += 16) {
        int src = csr[e];
        float4 v = h4[(size_t)src * 4 + l];
        a.x += v.x; a.y += v.y; a.z += v.z; a.w += v.w;
    }
    float4 u;
    u = shfl_xor_f4(a, 4);  a.x += u.x; a.y += u.y; a.z += u.z; a.w += u.w;
    u = shfl_xor_f4(a, 8);  a.x += u.x; a.y += u.y; a.z += u.z; a.w += u.w;
    u = shfl_xor_f4(a, 16); a.x += u.x; a.y += u.y; a.z += u.z; a.w += u.w;
    u = shfl_xor_f4(a, 32); a.x += u.x; a.y += u.y; a.z += u.z; a.w += u.w;
    if (g == 0) {
        float4 self = h4[(size_t)node * 4 + l];
        float di = dinv[node];
        float4 bb = ((const float4*)b2)[l];
        float4 v;
        v.x = di * (a.x + self.x) + bb.x;
        v.y = di * (a.y + self.y) + bb.y;
        v.z = di * (a.z + self.z) + bb.z;
        v.w = di * (a.w + self.w) + bb.w;
        // log_softmax over 16 classes spread across lanes 0..3 x 4 comps
        float m = fmaxf(fmaxf(v.x, v.y), fmaxf(v.z, v.w));
        m = fmaxf(m, __shfl_xor(m, 1, 64));
        m = fmaxf(m, __shfl_xor(m, 2, 64));
        float s = __expf(v.x - m) + __expf(v.y - m) + __expf(v.z - m) + __expf(v.w - m);
        s += __shfl_xor(s, 1, 64);
        s += __shfl_xor(s, 2, 64);
        float ls = m + __logf(s);
        float4 r = make_float4(v.x - ls, v.y - ls, v.z - ls, v.w - ls);
        ((float4*)out)[(size_t)node * 4 + l] = r;
    }
}

// ---------------- launch ----------------
extern "C" void kernel_launch(void* const* d_in, const int* in_sizes, int n_in,
                              void* d_out, int out_size, void* d_ws, size_t ws_size,
                              hipStream_t stream) {
    const float* x  = (const float*)d_in[0];
    const void* edges = d_in[1];
    const float* W1 = (const float*)d_in[2];
    const float* b1 = (const float*)d_in[3];
    const float* W2 = (const float*)d_in[4];
    const float* b2 = (const float*)d_in[5];
    float* out = (float*)d_out;

    const int N = in_sizes[0] / F_IN;   // 100000 (packing requires N < 131072)
    const int E = in_sizes[1] / 2;      // 3200000
    const int NBUK = (N + BNODES - 1) >> BSH;  // 196

    char* w = (char*)d_ws;
    size_t off = 0;
    auto take = [&](size_t bytes) {
        size_t o = off;
        off += (bytes + 15) & ~(size_t)15;
        return o;
    };
    float* hs1    = (float*)(w + take((size_t)N * F_HID * 4));
    float* out1   = (float*)(w + take((size_t)N * F_HID * 4));
    float* dinv   = (float*)(w + take((size_t)N * 4));
    int* row_ptr  = (int*)(w + take(((size_t)N + 1) * 4));
    int* bucket   = (int*)(w + take((size_t)E * 4));
    int* csr      = (int*)(w + take((size_t)E * 4));
    int* bcnt     = (int*)(w + take(1024));
    int* bbase    = (int*)(w + take(1040));
    int* bcur     = (int*)(w + take(1024));
    int* flag     = (int*)(w + take(16));
    float* hs2    = hs1;  // hs1 dead after gather1 -> reuse

    hipLaunchKernelGGL(k_detect, dim3(1), dim3(256), 0, stream, (const int*)edges, flag, bcnt);
    hipLaunchKernelGGL(k_bcount, dim3(512), dim3(256), 0, stream, edges, flag, bcnt, E, NBUK);
    hipLaunchKernelGGL(k_bscan, dim3(1), dim3(256), 0, stream, bcnt, bbase, bcur, NBUK, E);
    const int SB = (E + 256 * SK - 1) / (256 * SK);
    hipLaunchKernelGGL(k_bscatter, dim3(SB), dim3(256), 0, stream, edges, flag, bcur, bucket, E, NBUK);
    hipLaunchKernelGGL(k_build, dim3(NBUK), dim3(512), 0, stream, bucket, bbase, row_ptr, dinv, csr, N, NBUK, E);
    hipLaunchKernelGGL(k_gemm1, dim3((N + 127) / 128), dim3(256), 0, stream, x, W1, dinv, hs1, N);
    hipLaunchKernelGGL(k_gather1, dim3((N + 3) / 4), dim3(256), 0, stream, hs1, csr, row_ptr, dinv, b1, out1, N);
    hipLaunchKernelGGL(k_gemm2, dim3((N + 255) / 256), dim3(256), 0, stream, out1, W2, dinv, hs2, N);
    hipLaunchKernelGGL(k_gather2, dim3((N + 3) / 4), dim3(256), 0, stream, hs2, csr, row_ptr, dinv, b2, out, N);
}